// Round 6
// baseline (323.612 us; speedup 1.0000x reference)
//
#include <hip/hip_runtime.h>
#include <math.h>

#define BATCH 4096
#define T 128
#define HOR 24

#define LOG2E 1.44269504088896f
#define C2    2.88539008177793f   // 2*log2(e)

typedef _Float16 half2_t __attribute__((ext_vector_type(2)));
typedef _Float16 half8   __attribute__((ext_vector_type(8)));
typedef float f2  __attribute__((ext_vector_type(2)));
typedef float f4v __attribute__((ext_vector_type(4)));

__device__ __forceinline__ float fexp2(float x){ return __builtin_amdgcn_exp2f(x); }
__device__ __forceinline__ float frcp(float x){ return __builtin_amdgcn_rcpf(x); }
__device__ __forceinline__ float fsig(float x){ return frcp(1.0f + fexp2(-LOG2E*x)); }
__device__ __forceinline__ float ftanh(float x){ return fmaf(-2.0f, frcp(1.0f + fexp2(C2*x)), 1.0f); }
__device__ __forceinline__ half2_t bch(unsigned u){ return __builtin_bit_cast(half2_t,u); }
__device__ __forceinline__ unsigned pk2(float a,float b){ return __builtin_bit_cast(unsigned, __builtin_amdgcn_cvt_pkrtz(a,b)); }
// RNE f32-pair -> packed f16 (for exp2 values: keep full fp16 accuracy, no RTZ bias)
__device__ __forceinline__ unsigned pk2rne(float a,float b){
  half2_t h; h.x = (_Float16)a; h.y = (_Float16)b;
  return __builtin_bit_cast(unsigned, h);
}
__device__ __forceinline__ float e2c(float v){ return fexp2(fminf(v, 15.5f)); }
__device__ __forceinline__ float fdot2f(half2_t a, half2_t b, float c){
#if __has_builtin(__builtin_amdgcn_fdot2)
  return __builtin_amdgcn_fdot2(a,b,c,false);
#else
  return fmaf((float)a.x,(float)b.x, fmaf((float)a.y,(float)b.y,c));
#endif
}
__device__ __forceinline__ f2 pkfma(f2 a, f2 b, f2 c){ return __builtin_elementwise_fma(a,b,c); }

template <int CTRL, int RMASK>
__device__ __forceinline__ float dpp_add(float v) {
  int s = __builtin_amdgcn_update_dpp(0, __builtin_bit_cast(int, v), CTRL, RMASK, 0xf, true);
  return v + __builtin_bit_cast(float, s);
}
__device__ __forceinline__ float wavesum_dpp(float v) {
  v = dpp_add<0x111, 0xf>(v);
  v = dpp_add<0x112, 0xf>(v);
  v = dpp_add<0x114, 0xf>(v);
  v = dpp_add<0x118, 0xf>(v);
  v = dpp_add<0x142, 0xa>(v);
  v = dpp_add<0x143, 0xc>(v);
  return v;                     // total in lane 63
}
__device__ __forceinline__ float rdl63(float v){
  return __builtin_bit_cast(float, __builtin_amdgcn_readlane(__builtin_bit_cast(int, v), 63));
}

// Same-wave LDS write->read fence: in-order LDS per wave guarantees the data;
// the asm+sched_barrier stops the COMPILER reordering ds ops across it.
#define WAVE_LDS_FENCE() do {                                   \
    asm volatile("s_waitcnt lgkmcnt(0)" ::: "memory");          \
    __builtin_amdgcn_sched_barrier(0);                          \
  } while (0)

__device__ __forceinline__ void gru_mv(const _Float16* hrow,
    const unsigned* wr_r, const unsigned* wr_z, const unsigned* wr_n,
    float& ar0, float& ar1, float& az0, float& az1, float& an0, float& an1)
{
  const uint4* hq = (const uint4*)hrow;
  #pragma unroll
  for (int q = 0; q < 8; ++q) {
    uint4 hv = hq[q];
    ar0 = fdot2f(bch(hv.x), bch(wr_r[4*q+0]), ar0);
    az0 = fdot2f(bch(hv.x), bch(wr_z[4*q+0]), az0);
    an0 = fdot2f(bch(hv.x), bch(wr_n[4*q+0]), an0);
    ar1 = fdot2f(bch(hv.y), bch(wr_r[4*q+1]), ar1);
    az1 = fdot2f(bch(hv.y), bch(wr_z[4*q+1]), az1);
    an1 = fdot2f(bch(hv.y), bch(wr_n[4*q+1]), an1);
    ar0 = fdot2f(bch(hv.z), bch(wr_r[4*q+2]), ar0);
    az0 = fdot2f(bch(hv.z), bch(wr_z[4*q+2]), az0);
    an0 = fdot2f(bch(hv.z), bch(wr_n[4*q+2]), an0);
    ar1 = fdot2f(bch(hv.w), bch(wr_r[4*q+3]), ar1);
    az1 = fdot2f(bch(hv.w), bch(wr_z[4*q+3]), az1);
    an1 = fdot2f(bch(hv.w), bch(wr_n[4*q+3]), an1);
  }
}

__device__ __forceinline__ float proj_dot(const _Float16* base, const unsigned* udr)
{
  float acc = 0.f;
  const uint4* hb = (const uint4*)base;
  #pragma unroll
  for (int q = 0; q < 4; ++q) {
    uint4 hv = hb[q];
    acc = fdot2f(bch(hv.x), bch(udr[4*q+0]), acc);
    acc = fdot2f(bch(hv.y), bch(udr[4*q+1]), acc);
    acc = fdot2f(bch(hv.z), bch(udr[4*q+2]), acc);
    acc = fdot2f(bch(hv.w), bch(udr[4*q+3]), acc);
  }
  return acc;
}

__device__ __forceinline__ half8 cvt8(f4v a, f4v b){
  half8 h;
  h[0]=(_Float16)a.x; h[1]=(_Float16)a.y; h[2]=(_Float16)a.z; h[3]=(_Float16)a.w;
  h[4]=(_Float16)b.x; h[5]=(_Float16)b.y; h[6]=(_Float16)b.z; h[7]=(_Float16)b.w;
  return h;
}

// ============ Kernel A: encoder — barrier-free 4-elem waves + redistribute =
// R20: evidence from R15-R18: (a) 4-wave barrier version stalls ~87% (latency,
// cross-wave coupling); (b) 1-wave version is trans-issue-bound (96 trans on
// one SIMD). This version gets BOTH independence and low trans: each wave owns
// 4 elems (cols 0-3; cols 4-15 zero) and all 64 units -> 24 gate MFMAs + 6 Eh
// MFMAs; C-results are redistributed through a per-wave LDS buffer so all 64
// lanes each evaluate 4 (elem,unit) gates -> 24+8 trans/wave (R15 level).
// ZERO s_barrier; all LDS traffic is same-wave (in-order).
__global__ __launch_bounds__(256, 1)
void darnn_enc(const float* __restrict__ x,
               const float* __restrict__ W_ih_e, const float* __restrict__ W_hh_e,
               const float* __restrict__ b_ih_e, const float* __restrict__ b_hh_e,
               const float* __restrict__ U_d, const float* __restrict__ W_out,
               unsigned* __restrict__ hpG, float* __restrict__ hTG)
{
  const int tid = threadIdx.x;
  const int w = tid >> 6;
  const int l = tid & 63;
  const int c = l & 15;          // MFMA column (elem for c<4) / A-row
  const int q = l >> 4;          // quad
  const int e0 = blockIdx.x * 16 + 4*w;  // wave's first elem
  const int eL = c & 3;          // post-redistribute: lane's elem slot
  const int ML = c >> 2;         // post-redistribute: lane's unit block
  const int m0L = 16*ML + 4*q;   // lane's 4 hidden units

  __shared__ __align__(16) _Float16 He[4][16*72];  // per-wave h[col][72]
  __shared__ __align__(16) unsigned xw[4][4*65];   // per-wave x fp16-pairs
  __shared__ __align__(16) unsigned Cb[4][12*68];  // per-wave C redistribute

  _Float16* Hw  = He[w];
  unsigned* xww = xw[w];
  unsigned* Cbw = Cb[w];

  // ---- stage x (4 elems) + zero He (cols 4-15 stay zero forever) ----
  for (int idx = l; idx < 256; idx += 64) {
    int e = idx >> 6, j = idx & 63;
    f2 g = ((const f2*)(x + (size_t)(e0+e)*T))[j];
    xww[e*65 + j] = pk2(g.x, g.y);
  }
  for (int idx = l; idx < 576; idx += 64) ((unsigned*)Hw)[idx] = 0;

  // ---- A-frags: ALL W_hh rows (r/z/n x 4 M-blocks) ----
  half8 Ar[4][2], Az[4][2], An[4][2];
  #pragma unroll
  for (int M = 0; M < 4; ++M) {
    #pragma unroll
    for (int kap = 0; kap < 2; ++kap) {
      const f4v* pr = (const f4v*)(W_hh_e + (size_t)(16*M + c)*64       + 32*kap + 8*q);
      const f4v* pz = (const f4v*)(W_hh_e + (size_t)(64 + 16*M + c)*64  + 32*kap + 8*q);
      const f4v* pn = (const f4v*)(W_hh_e + (size_t)(128 + 16*M + c)*64 + 32*kap + 8*q);
      Ar[M][kap] = cvt8(pr[0], pr[1]);
      Az[M][kap] = cvt8(pz[0], pz[1]);
      An[M][kap] = cvt8(pn[0], pn[1]);
    }
  }
  // ---- Eh A-frags: U_d rows (xC2) + W_out ctx row (lane c==0 rows only) ----
  half8 AX[2][2], AW[2];
  #pragma unroll
  for (int M = 0; M < 2; ++M) {
    #pragma unroll
    for (int kap = 0; kap < 2; ++kap) {
      const f4v* p = (const f4v*)(U_d + (size_t)(16*M + c)*64 + 32*kap + 8*q);
      AX[M][kap] = cvt8(p[0] * C2, p[1] * C2);
    }
  }
  AW[0] = (half8){0,0,0,0,0,0,0,0};
  AW[1] = (half8){0,0,0,0,0,0,0,0};
  if (c == 0) {
    #pragma unroll
    for (int kap = 0; kap < 2; ++kap) {
      const f4v* p = (const f4v*)(W_out + 64 + 32*kap + 8*q);
      AW[kap] = cvt8(p[0], p[1]);
    }
  }
  // ---- per-lane gate params for units m0L..m0L+3 ----
  f4v wih0 = *(const f4v*)(W_ih_e + m0L);
  f4v wih1 = *(const f4v*)(W_ih_e + 64 + m0L);
  f4v wih2 = *(const f4v*)(W_ih_e + 128 + m0L);
  f4v bb0  = *(const f4v*)(b_ih_e + m0L)      + *(const f4v*)(b_hh_e + m0L);
  f4v bb1  = *(const f4v*)(b_ih_e + 64 + m0L) + *(const f4v*)(b_hh_e + 64 + m0L);
  f4v bi2  = *(const f4v*)(b_ih_e + 128 + m0L);
  f4v bh2  = *(const f4v*)(b_hh_e + 128 + m0L);
  f4v hreg = {0,0,0,0};
  const f4v z4 = {0,0,0,0};
  unsigned* hpBc = hpG + (size_t)(e0 + eL) * 2176;  // Eh store base (c<4 only)

  WAVE_LDS_FENCE();  // staging writes visible to this wave's reads

  // ---- 128 steps, no barriers ----
  #pragma unroll 1
  for (int t = 0; t < T; ++t) {
    half8 B0 = __builtin_bit_cast(half8, *(const uint4*)(Hw + c*72 + 8*q));
    half8 B1 = __builtin_bit_cast(half8, *(const uint4*)(Hw + c*72 + 32 + 8*q));
    if (t > 0) {   // Eh/hw for t-1 from h_{t-1} (= B-frags); producer layout
      f4v cu0 = __builtin_amdgcn_mfma_f32_16x16x32_f16(AX[0][0], B0, z4, 0,0,0);
      cu0     = __builtin_amdgcn_mfma_f32_16x16x32_f16(AX[0][1], B1, cu0, 0,0,0);
      f4v cu1 = __builtin_amdgcn_mfma_f32_16x16x32_f16(AX[1][0], B0, z4, 0,0,0);
      cu1     = __builtin_amdgcn_mfma_f32_16x16x32_f16(AX[1][1], B1, cu1, 0,0,0);
      f4v cw  = __builtin_amdgcn_mfma_f32_16x16x32_f16(AW[0],    B0, z4, 0,0,0);
      cw      = __builtin_amdgcn_mfma_f32_16x16x32_f16(AW[1],    B1, cw, 0,0,0);
      if (c < 4) {
        unsigned* hpE = hpBc + (t-1)*17;
        hpE[2*q]     = pk2rne(e2c(cu0[0]), e2c(cu0[1]));
        hpE[2*q+1]   = pk2rne(e2c(cu0[2]), e2c(cu0[3]));
        hpE[8+2*q]   = pk2rne(e2c(cu1[0]), e2c(cu1[1]));
        hpE[8+2*q+1] = pk2rne(e2c(cu1[2]), e2c(cu1[3]));
        if (q == 0) ((float*)hpE)[16] = cw[0];
      }
    }
    // gate MFMAs, write C to redistribute buffer (cols 0-3 hold real elems)
    #pragma unroll
    for (int M = 0; M < 4; ++M) {
      f4v gr = __builtin_amdgcn_mfma_f32_16x16x32_f16(Ar[M][0], B0, z4, 0,0,0);
      gr     = __builtin_amdgcn_mfma_f32_16x16x32_f16(Ar[M][1], B1, gr, 0,0,0);
      f4v gz = __builtin_amdgcn_mfma_f32_16x16x32_f16(Az[M][0], B0, z4, 0,0,0);
      gz     = __builtin_amdgcn_mfma_f32_16x16x32_f16(Az[M][1], B1, gz, 0,0,0);
      f4v gn = __builtin_amdgcn_mfma_f32_16x16x32_f16(An[M][0], B0, z4, 0,0,0);
      gn     = __builtin_amdgcn_mfma_f32_16x16x32_f16(An[M][1], B1, gn, 0,0,0);
      if (c < 4) {
        *(uint4*)&Cbw[(0*4 + c)*68 + (M*4+q)*4] = __builtin_bit_cast(uint4, gr);
        *(uint4*)&Cbw[(1*4 + c)*68 + (M*4+q)*4] = __builtin_bit_cast(uint4, gz);
        *(uint4*)&Cbw[(2*4 + c)*68 + (M*4+q)*4] = __builtin_bit_cast(uint4, gn);
      }
    }
    WAVE_LDS_FENCE();
    // redistribute: every lane picks its (elem eL, block ML) slice
    f4v gR = __builtin_bit_cast(f4v, *(const uint4*)&Cbw[(0*4+eL)*68 + (ML*4+q)*4]);
    f4v gZ = __builtin_bit_cast(f4v, *(const uint4*)&Cbw[(1*4+eL)*68 + (ML*4+q)*4]);
    f4v gN = __builtin_bit_cast(f4v, *(const uint4*)&Cbw[(2*4+eL)*68 + (ML*4+q)*4]);
    float xc = (float)((const _Float16*)xww)[eL*130 + t];
    f4v hn;
    #pragma unroll
    for (int i = 0; i < 4; ++i) {
      float r  = fsig(fmaf(xc, wih0[i], bb0[i]) + gR[i]);
      float zf = fsig(fmaf(xc, wih1[i], bb1[i]) + gZ[i]);
      float n  = ftanh(fmaf(xc, wih2[i], bi2[i]) + r*(gN[i] + bh2[i]));
      float h  = fmaf(zf, hreg[i] - n, n);
      hreg[i] = h;
      hn[i] = h;
    }
    uint2 wv; wv.x = pk2(hn[0], hn[1]); wv.y = pk2(hn[2], hn[3]);
    *(uint2*)(Hw + eL*72 + m0L) = wv;
    WAVE_LDS_FENCE();
  }
  // ---- epilogue: Eh/hw for t=127 from h_127 ----
  {
    half8 B0 = __builtin_bit_cast(half8, *(const uint4*)(Hw + c*72 + 8*q));
    half8 B1 = __builtin_bit_cast(half8, *(const uint4*)(Hw + c*72 + 32 + 8*q));
    f4v cu0 = __builtin_amdgcn_mfma_f32_16x16x32_f16(AX[0][0], B0, z4, 0,0,0);
    cu0     = __builtin_amdgcn_mfma_f32_16x16x32_f16(AX[0][1], B1, cu0, 0,0,0);
    f4v cu1 = __builtin_amdgcn_mfma_f32_16x16x32_f16(AX[1][0], B0, z4, 0,0,0);
    cu1     = __builtin_amdgcn_mfma_f32_16x16x32_f16(AX[1][1], B1, cu1, 0,0,0);
    f4v cw  = __builtin_amdgcn_mfma_f32_16x16x32_f16(AW[0],    B0, z4, 0,0,0);
    cw      = __builtin_amdgcn_mfma_f32_16x16x32_f16(AW[1],    B1, cw, 0,0,0);
    if (c < 4) {
      unsigned* hpE = hpBc + 127*17;
      hpE[2*q]     = pk2rne(e2c(cu0[0]), e2c(cu0[1]));
      hpE[2*q+1]   = pk2rne(e2c(cu0[2]), e2c(cu0[3]));
      hpE[8+2*q]   = pk2rne(e2c(cu1[0]), e2c(cu1[1]));
      hpE[8+2*q+1] = pk2rne(e2c(cu1[2]), e2c(cu1[3]));
      if (q == 0) ((float*)hpE)[16] = cw[0];
    }
  }
  // ---- h_T (fp32): lane owns (eL, units m0L..+3) ----
  #pragma unroll
  for (int i = 0; i < 4; ++i)
    hTG[(size_t)(e0 + eL)*64 + m0L + i] = hreg[i];
}

// ============ Kernel B: decoder — 2-elem ILP per wave (R16/R3 proven) ======
__global__ __launch_bounds__(128, 2)
void darnn_dec(const float* __restrict__ W_init, const float* __restrict__ b_init,
               const float* __restrict__ W_ih_d, const float* __restrict__ W_hh_d,
               const float* __restrict__ b_ih_d, const float* __restrict__ b_hh_d,
               const float* __restrict__ W_d, const float* __restrict__ v_d,
               const float* __restrict__ W_out, const float* __restrict__ b_out,
               const float* __restrict__ y0,
               const unsigned* __restrict__ hpG, const float* __restrict__ hTG,
               float* __restrict__ out)
{
  const int tid = threadIdx.x;
  const int wid = tid >> 6;
  const int l   = tid & 63;
  const int bA  = 4*blockIdx.x + 2*wid;
  const int bB  = bA + 1;
  const int a    = l & 31;
  const int half = l >> 5;

  __shared__ __align__(16) unsigned char smem[36928];
  unsigned char* wbp = smem + wid*18464;
  unsigned* hpA   = (unsigned*)wbp;                  // Eh fp16 pairs (+hw f32)
  unsigned* hpB   = (unsigned*)(wbp + 8704);
  _Float16* ringA = (_Float16*)(wbp + 17408);
  _Float16* ringB = (_Float16*)(wbp + 17536);
  float*    dpA   = (float*)(wbp + 17664);           // Edp = exp2(C2*W_d.d)
  float*    dpB   = (float*)(wbp + 17792);
  float*    hTA   = (float*)(wbp + 17920);
  float*    hTB   = (float*)(wbp + 18176);

  {
    const uint4* sA = (const uint4*)(hpG + (size_t)bA * 2176);
    const uint4* sB = (const uint4*)(hpG + (size_t)bB * 2176);
    #pragma unroll
    for (int it = 0; it < 8; ++it) {
      ((uint4*)hpA)[it*64 + l] = sA[it*64 + l];
      ((uint4*)hpB)[it*64 + l] = sB[it*64 + l];
    }
    const unsigned* rA = hpG + (size_t)bA*2176 + 2048;
    const unsigned* rB = hpG + (size_t)bB*2176 + 2048;
    hpA[2048 + l] = rA[l];      hpA[2112 + l] = rA[64 + l];
    hpB[2048 + l] = rB[l];      hpB[2112 + l] = rB[64 + l];
  }
  hTA[l] = hTG[(size_t)bA*64 + l];
  hTB[l] = hTG[(size_t)bB*64 + l];

  unsigned wr_r[32], wr_z[32], wr_n[32];
  {
    const f4v* wp = (const f4v*)W_hh_d;
    #pragma unroll
    for (int k = 0; k < 16; ++k) {
      f4v vr = wp[l*16 + k];
      f4v vz = wp[(64 + l)*16 + k];
      f4v vn = wp[(128 + l)*16 + k];
      wr_r[2*k] = pk2(vr.x, vr.y); wr_r[2*k+1] = pk2(vr.z, vr.w);
      wr_z[2*k] = pk2(vz.x, vz.y); wr_z[2*k+1] = pk2(vz.z, vz.w);
      wr_n[2*k] = pk2(vn.x, vn.y); wr_n[2*k+1] = pk2(vn.z, vn.w);
    }
  }
  float wih0 = W_ih_d[l], wih1 = W_ih_d[64+l], wih2 = W_ih_d[128+l];
  float bb0  = b_ih_d[l] + b_hh_d[l];
  float bb1  = b_ih_d[64+l] + b_hh_d[64+l];
  float bih2 = b_ih_d[128+l], bhh2 = b_hh_d[128+l];
  unsigned udr[16];
  {
    const f2* up = (const f2*)(W_d + a*64 + half*32);
    #pragma unroll
    for (int k = 0; k < 16; ++k) { f2 f = up[k]; udr[k] = pk2(f.x, f.y); }
  }
  float dprevA, dprevB;
  {
    const f4v* wi = (const f4v*)(W_init + l*64);
    const f4v* ga = (const f4v*)hTA;
    const f4v* gb = (const f4v*)hTB;
    f2 aa0={0,0}, aa1={0,0}, ba0={0,0}, ba1={0,0};
    #pragma unroll
    for (int k = 0; k < 16; ++k) {
      f4v wv = wi[k];
      f4v va = ga[k], vb = gb[k];
      aa0 = pkfma(wv.xy, va.xy, aa0);
      aa1 = pkfma(wv.zw, va.zw, aa1);
      ba0 = pkfma(wv.xy, vb.xy, ba0);
      ba1 = pkfma(wv.zw, vb.zw, ba1);
    }
    float bi = b_init[l];
    dprevA = bi + (aa0.x + aa0.y) + (aa1.x + aa1.y);
    dprevB = bi + (ba0.x + ba0.y) + (ba1.x + ba1.y);
  }
  float wout1 = W_out[l];
  float hw0A = __builtin_bit_cast(float, hpA[l*17 + 16]);
  float hw1A = __builtin_bit_cast(float, hpA[(64 + l)*17 + 16]);
  float hw0B = __builtin_bit_cast(float, hpB[l*17 + 16]);
  float hw1B = __builtin_bit_cast(float, hpB[(64 + l)*17 + 16]);
  float oprevA = y0[0], oprevB = y0[0];
  float bo = b_out[0];
  float c1;
  {
    float sv = v_d[a];
    sv += __shfl_xor(sv, 16); sv += __shfl_xor(sv, 8);
    sv += __shfl_xor(sv, 4);  sv += __shfl_xor(sv, 2); sv += __shfl_xor(sv, 1);
    c1 = LOG2E * sv;
  }
  ringA[l] = (_Float16)dprevA;
  ringB[l] = (_Float16)dprevB;

  const unsigned* hprA0 = hpA + l*17;
  const unsigned* hprA1 = hpA + (64 + l)*17;
  const unsigned* hprB0 = hpB + l*17;
  const unsigned* hprB1 = hpB + (64 + l)*17;

  #pragma unroll 1
  for (int s = 0; s < HOR; ++s) {
    float ar0A=0,ar1A=0,az0A=0,az1A=0,an0A=0,an1A=0;
    float ar0B=0,ar1B=0,az0B=0,az1B=0,an0B=0,an1B=0;
    gru_mv(ringA, wr_r, wr_z, wr_n, ar0A,ar1A,az0A,az1A,an0A,an1A);
    gru_mv(ringB, wr_r, wr_z, wr_n, ar0B,ar1B,az0B,az1B,an0B,an1B);
    float rA = fsig(fmaf(oprevA, wih0, bb0) + ar0A + ar1A);
    float zA = fsig(fmaf(oprevA, wih1, bb1) + az0A + az1A);
    float nA = ftanh(fmaf(oprevA, wih2, bih2) + rA * (an0A + an1A + bhh2));
    float dnewA = fmaf(zA, dprevA - nA, nA);
    float rB = fsig(fmaf(oprevB, wih0, bb0) + ar0B + ar1B);
    float zB = fsig(fmaf(oprevB, wih1, bb1) + az0B + az1B);
    float nB = ftanh(fmaf(oprevB, wih2, bih2) + rB * (an0B + an1B + bhh2));
    float dnewB = fmaf(zB, dprevB - nB, nB);
    dprevA = dnewA; dprevB = dnewB;
    ringA[l] = (_Float16)dnewA;
    ringB[l] = (_Float16)dnewB;
    {
      float accA = proj_dot(ringA + half*32, udr);
      float accB = proj_dot(ringB + half*32, udr);
      accA += __shfl_xor(accA, 32);
      accB += __shfl_xor(accB, 32);
      if (l < 32) {
        dpA[l] = fexp2(C2 * accA);   // Edp: one wave exp2 per elem per step
        dpB[l] = fexp2(C2 * accB);
      }
    }
    float rs0A = 0.f, rs1A = 0.f, rs0B = 0.f, rs1B = 0.f;
    #pragma unroll
    for (int j2 = 0; j2 < 8; ++j2) {
      f4v edA = *(const f4v*)&dpA[4*j2];
      f4v edB = *(const f4v*)&dpB[4*j2];
      half2_t haA0 = bch(hprA0[2*j2]), hbA0 = bch(hprA0[2*j2+1]);
      half2_t haA1 = bch(hprA1[2*j2]), hbA1 = bch(hprA1[2*j2+1]);
      half2_t haB0 = bch(hprB0[2*j2]), hbB0 = bch(hprB0[2*j2+1]);
      half2_t haB1 = bch(hprB1[2*j2]), hbB1 = bch(hprB1[2*j2+1]);
      float v0 = v_d[4*j2], v1 = v_d[4*j2+1], v2 = v_d[4*j2+2], v3 = v_d[4*j2+3];
      // sigma = 1/(1 + Edp*Eh): fma_mix + rcp, no per-element exp2
      rs0A = fmaf(v0, frcp(fmaf(edA.x, (float)haA0.x, 1.0f)), rs0A);
      rs0B = fmaf(v0, frcp(fmaf(edB.x, (float)haB0.x, 1.0f)), rs0B);
      rs0A = fmaf(v1, frcp(fmaf(edA.y, (float)haA0.y, 1.0f)), rs0A);
      rs0B = fmaf(v1, frcp(fmaf(edB.y, (float)haB0.y, 1.0f)), rs0B);
      rs0A = fmaf(v2, frcp(fmaf(edA.z, (float)hbA0.x, 1.0f)), rs0A);
      rs0B = fmaf(v2, frcp(fmaf(edB.z, (float)hbB0.x, 1.0f)), rs0B);
      rs0A = fmaf(v3, frcp(fmaf(edA.w, (float)hbA0.y, 1.0f)), rs0A);
      rs0B = fmaf(v3, frcp(fmaf(edB.w, (float)hbB0.y, 1.0f)), rs0B);
      rs1A = fmaf(v0, frcp(fmaf(edA.x, (float)haA1.x, 1.0f)), rs1A);
      rs1B = fmaf(v0, frcp(fmaf(edB.x, (float)haB1.x, 1.0f)), rs1B);
      rs1A = fmaf(v1, frcp(fmaf(edA.y, (float)haA1.y, 1.0f)), rs1A);
      rs1B = fmaf(v1, frcp(fmaf(edB.y, (float)haB1.y, 1.0f)), rs1B);
      rs1A = fmaf(v2, frcp(fmaf(edA.z, (float)hbA1.x, 1.0f)), rs1A);
      rs1B = fmaf(v2, frcp(fmaf(edB.z, (float)hbB1.x, 1.0f)), rs1B);
      rs1A = fmaf(v3, frcp(fmaf(edA.w, (float)hbA1.y, 1.0f)), rs1A);
      rs1B = fmaf(v3, frcp(fmaf(edB.w, (float)hbB1.y, 1.0f)), rs1B);
    }
    float e0A = fexp2(fmaf(-C2, rs0A, c1));
    float e1A = fexp2(fmaf(-C2, rs1A, c1));
    float e0B = fexp2(fmaf(-C2, rs0B, c1));
    float e1B = fexp2(fmaf(-C2, rs1B, c1));
    float P0A = rdl63(wavesum_dpp(e0A + e1A));
    float P1A = rdl63(wavesum_dpp(fmaf(e0A, hw0A, e1A * hw1A)));
    float P2A = rdl63(wavesum_dpp(wout1 * dnewA));
    float P0B = rdl63(wavesum_dpp(e0B + e1B));
    float P1B = rdl63(wavesum_dpp(fmaf(e0B, hw0B, e1B * hw1B)));
    float P2B = rdl63(wavesum_dpp(wout1 * dnewB));
    float oA = fmaf(P1A, frcp(P0A), P2A + bo);
    float oB = fmaf(P1B, frcp(P0B), P2B + bo);
    if (l == 0) {
      out[(size_t)bA * HOR + s] = oA;
      out[(size_t)bB * HOR + s] = oB;
    }
    oprevA = oA; oprevB = oB;
  }
}

extern "C" void kernel_launch(void* const* d_in, const int* in_sizes, int n_in,
                              void* d_out, int out_size, void* d_ws, size_t ws_size,
                              hipStream_t stream) {
  const float* x      = (const float*)d_in[0];
  const float* W_ih_e = (const float*)d_in[1];
  const float* W_hh_e = (const float*)d_in[2];
  const float* b_ih_e = (const float*)d_in[3];
  const float* b_hh_e = (const float*)d_in[4];
  // d_in[5..8] = W_e, U_e, b_e, v_e : dead (softmax over size-1 axis == 1)
  const float* W_init = (const float*)d_in[9];
  const float* b_init = (const float*)d_in[10];
  const float* W_ih_d = (const float*)d_in[11];
  const float* W_hh_d = (const float*)d_in[12];
  const float* b_ih_d = (const float*)d_in[13];
  const float* b_hh_d = (const float*)d_in[14];
  const float* W_d    = (const float*)d_in[15];
  const float* U_d    = (const float*)d_in[16];
  const float* v_d    = (const float*)d_in[17];
  const float* W_out  = (const float*)d_in[18];
  const float* b_out  = (const float*)d_in[19];
  const float* y0     = (const float*)d_in[20];
  float* outp = (float*)d_out;

  unsigned* hpG = (unsigned*)d_ws;
  float*    hTG = (float*)((char*)d_ws + (size_t)BATCH * 2176 * 4);

  darnn_enc<<<BATCH/16, 256, 0, stream>>>(x, W_ih_e, W_hh_e, b_ih_e, b_hh_e,
      U_d, W_out, hpG, hTG);
  darnn_dec<<<BATCH/4, 128, 0, stream>>>(W_init, b_init, W_ih_d, W_hh_d,
      b_ih_d, b_hh_d, W_d, v_d, W_out, b_out, y0, hpG, hTG, outp);
}

// Round 7
// 292.586 us; speedup vs baseline: 1.1060x; 1.1060x over previous
//
#include <hip/hip_runtime.h>
#include <math.h>

#define BATCH 4096
#define T 128
#define HOR 24

#define LOG2E 1.44269504088896f
#define C2    2.88539008177793f   // 2*log2(e)

typedef _Float16 half2_t __attribute__((ext_vector_type(2)));
typedef _Float16 half8   __attribute__((ext_vector_type(8)));
typedef float f2  __attribute__((ext_vector_type(2)));
typedef float f4v __attribute__((ext_vector_type(4)));

__device__ __forceinline__ float fexp2(float x){ return __builtin_amdgcn_exp2f(x); }
__device__ __forceinline__ float frcp(float x){ return __builtin_amdgcn_rcpf(x); }
__device__ __forceinline__ float fsig(float x){ return frcp(1.0f + fexp2(-LOG2E*x)); }
__device__ __forceinline__ float ftanh(float x){ return fmaf(-2.0f, frcp(1.0f + fexp2(C2*x)), 1.0f); }
__device__ __forceinline__ half2_t bch(unsigned u){ return __builtin_bit_cast(half2_t,u); }
__device__ __forceinline__ unsigned pk2(float a,float b){ return __builtin_bit_cast(unsigned, __builtin_amdgcn_cvt_pkrtz(a,b)); }
// RNE f32-pair -> packed f16 (for exp2 values: keep full fp16 accuracy, no RTZ bias)
__device__ __forceinline__ unsigned pk2rne(float a,float b){
  half2_t h; h.x = (_Float16)a; h.y = (_Float16)b;
  return __builtin_bit_cast(unsigned, h);
}
__device__ __forceinline__ float fdot2f(half2_t a, half2_t b, float c){
#if __has_builtin(__builtin_amdgcn_fdot2)
  return __builtin_amdgcn_fdot2(a,b,c,false);
#else
  return fmaf((float)a.x,(float)b.x, fmaf((float)a.y,(float)b.y,c));
#endif
}
__device__ __forceinline__ f2 pkfma(f2 a, f2 b, f2 c){ return __builtin_elementwise_fma(a,b,c); }

template <int CTRL, int RMASK>
__device__ __forceinline__ float dpp_add(float v) {
  int s = __builtin_amdgcn_update_dpp(0, __builtin_bit_cast(int, v), CTRL, RMASK, 0xf, true);
  return v + __builtin_bit_cast(float, s);
}
__device__ __forceinline__ float wavesum_dpp(float v) {
  v = dpp_add<0x111, 0xf>(v);
  v = dpp_add<0x112, 0xf>(v);
  v = dpp_add<0x114, 0xf>(v);
  v = dpp_add<0x118, 0xf>(v);
  v = dpp_add<0x142, 0xa>(v);
  v = dpp_add<0x143, 0xc>(v);
  return v;                     // total in lane 63
}
__device__ __forceinline__ float rdl63(float v){
  return __builtin_bit_cast(float, __builtin_amdgcn_readlane(__builtin_bit_cast(int, v), 63));
}

// Barrier that does NOT drain vmcnt: LDS producer/consumer ordering only.
#define WG_BARRIER_LDS() do {                                   \
    asm volatile("s_waitcnt lgkmcnt(0)" ::: "memory");          \
    __builtin_amdgcn_s_barrier();                               \
  } while (0)

__device__ __forceinline__ void gru_mv(const _Float16* hrow,
    const unsigned* wr_r, const unsigned* wr_z, const unsigned* wr_n,
    float& ar0, float& ar1, float& az0, float& az1, float& an0, float& an1)
{
  const uint4* hq = (const uint4*)hrow;
  #pragma unroll
  for (int q = 0; q < 8; ++q) {
    uint4 hv = hq[q];
    ar0 = fdot2f(bch(hv.x), bch(wr_r[4*q+0]), ar0);
    az0 = fdot2f(bch(hv.x), bch(wr_z[4*q+0]), az0);
    an0 = fdot2f(bch(hv.x), bch(wr_n[4*q+0]), an0);
    ar1 = fdot2f(bch(hv.y), bch(wr_r[4*q+1]), ar1);
    az1 = fdot2f(bch(hv.y), bch(wr_z[4*q+1]), az1);
    an1 = fdot2f(bch(hv.y), bch(wr_n[4*q+1]), an1);
    ar0 = fdot2f(bch(hv.z), bch(wr_r[4*q+2]), ar0);
    az0 = fdot2f(bch(hv.z), bch(wr_z[4*q+2]), az0);
    an0 = fdot2f(bch(hv.z), bch(wr_n[4*q+2]), an0);
    ar1 = fdot2f(bch(hv.w), bch(wr_r[4*q+3]), ar1);
    az1 = fdot2f(bch(hv.w), bch(wr_z[4*q+3]), az1);
    an1 = fdot2f(bch(hv.w), bch(wr_n[4*q+3]), an1);
  }
}

__device__ __forceinline__ float proj_dot(const _Float16* base, const unsigned* udr)
{
  float acc = 0.f;
  const uint4* hb = (const uint4*)base;
  #pragma unroll
  for (int q = 0; q < 4; ++q) {
    uint4 hv = hb[q];
    acc = fdot2f(bch(hv.x), bch(udr[4*q+0]), acc);
    acc = fdot2f(bch(hv.y), bch(udr[4*q+1]), acc);
    acc = fdot2f(bch(hv.z), bch(udr[4*q+2]), acc);
    acc = fdot2f(bch(hv.w), bch(udr[4*q+3]), acc);
  }
  return acc;
}

__device__ __forceinline__ half8 cvt8(f4v a, f4v b){
  half8 h;
  h[0]=(_Float16)a.x; h[1]=(_Float16)a.y; h[2]=(_Float16)a.z; h[3]=(_Float16)a.w;
  h[4]=(_Float16)b.x; h[5]=(_Float16)b.y; h[6]=(_Float16)b.z; h[7]=(_Float16)b.w;
  return h;
}

// ============ Kernel A: encoder — R15 (best measured: ~148 us) =============
// R21: after 5 failed encoder restructures (store-drain, chunked dump, dead-
// column 2-block, single-wave, barrier-free redistribute), R15's 4-wave
// m-split remains the best real-bench encoder. Restored verbatim.
__global__ __launch_bounds__(256, 1)
void darnn_enc(const float* __restrict__ x,
               const float* __restrict__ W_ih_e, const float* __restrict__ W_hh_e,
               const float* __restrict__ b_ih_e, const float* __restrict__ b_hh_e,
               const float* __restrict__ U_d, const float* __restrict__ W_out,
               unsigned* __restrict__ hpG, float* __restrict__ hTG)
{
  const int tid = threadIdx.x;
  const int w = tid >> 6;        // wave 0..3: owns hidden units [16w,16w+16)
  const int l = tid & 63;
  const int c = l & 15;          // MFMA column = element slot
  const int q = l >> 4;          // quad
  const int e0 = blockIdx.x * 16;
  const int m0 = 16*w + 4*q;     // first of this lane's 4 hidden units

  __shared__ __align__(16) _Float16 He[2][16*72]; // ping-pong h[e][k], pad 72
  __shared__ __align__(16) unsigned xw[16*65];    // x fp16-pairs [e][65]

  // ---- stage x + zero He[0] (cooperative, all 256 threads) ----
  for (int idx = tid; idx < 16*64; idx += 256) {
    int e = idx >> 6, j = idx & 63;
    f2 g = ((const f2*)(x + (size_t)(e0+e)*T))[j];
    xw[e*65 + j] = pk2(g.x, g.y);
  }
  for (int idx = tid; idx < 576; idx += 256) ((unsigned*)He[0])[idx] = 0;

  // ---- A-frags: this wave's W_hh rows (r/z/n), 6 half8 ----
  half8 Ar[2], Az[2], An[2];
  #pragma unroll
  for (int kap = 0; kap < 2; ++kap) {
    const f4v* pr = (const f4v*)(W_hh_e + (size_t)(16*w + c)*64       + 32*kap + 8*q);
    const f4v* pz = (const f4v*)(W_hh_e + (size_t)(64 + 16*w + c)*64  + 32*kap + 8*q);
    const f4v* pn = (const f4v*)(W_hh_e + (size_t)(128 + 16*w + c)*64 + 32*kap + 8*q);
    Ar[kap] = cvt8(pr[0], pr[1]);
    Az[kap] = cvt8(pz[0], pz[1]);
    An[kap] = cvt8(pn[0], pn[1]);
  }
  // ---- Hp/hw A-frags: wave0 -> U_d rows 0..15 (xC2), wave1 -> rows 16..31,
  //      wave2 -> W_out2 (row 0 only), wave3 -> none ----
  half8 AX[2] = {{0,0,0,0,0,0,0,0},{0,0,0,0,0,0,0,0}};
  if (w < 2) {
    #pragma unroll
    for (int kap = 0; kap < 2; ++kap) {
      const f4v* p = (const f4v*)(U_d + (size_t)(16*w + c)*64 + 32*kap + 8*q);
      AX[kap] = cvt8(p[0] * C2, p[1] * C2);
    }
  } else if (w == 2 && c == 0) {
    #pragma unroll
    for (int kap = 0; kap < 2; ++kap) {
      const f4v* p = (const f4v*)(W_out + 64 + 32*kap + 8*q);
      AX[kap] = cvt8(p[0], p[1]);
    }
  }
  // ---- per-lane combine params for m0..m0+3 ----
  f4v wih0 = *(const f4v*)(W_ih_e + m0);
  f4v wih1 = *(const f4v*)(W_ih_e + 64 + m0);
  f4v wih2 = *(const f4v*)(W_ih_e + 128 + m0);
  f4v bb0  = *(const f4v*)(b_ih_e + m0)      + *(const f4v*)(b_hh_e + m0);
  f4v bb1  = *(const f4v*)(b_ih_e + 64 + m0) + *(const f4v*)(b_hh_e + 64 + m0);
  f4v bi2  = *(const f4v*)(b_ih_e + 128 + m0);
  f4v bh2  = *(const f4v*)(b_hh_e + 128 + m0);
  f4v hreg = {0,0,0,0};
  const f4v z4 = {0,0,0,0};
  unsigned* hpB = hpG + (size_t)(e0 + c) * 2176;

  __syncthreads();   // once: x staging (global loads) may drain here, fine

  // ---- 128 steps: read He[t&1], write He[(t+1)&1], 1 LDS-barrier/step ----
  #pragma unroll 1
  for (int t = 0; t < T; ++t) {
    const _Float16* Hc = He[t & 1];
    half8 B0 = __builtin_bit_cast(half8, *(const uint4*)(Hc + c*72 + 8*q));
    half8 B1 = __builtin_bit_cast(half8, *(const uint4*)(Hc + c*72 + 32 + 8*q));
    if (t > 0) {           // Eh/hw for t-1 from h_{t-1} (= the B-frags)
      if (w < 2) {
        f4v cu = __builtin_amdgcn_mfma_f32_16x16x32_f16(AX[0], B0, z4, 0,0,0);
        cu     = __builtin_amdgcn_mfma_f32_16x16x32_f16(AX[1], B1, cu, 0,0,0);
        unsigned* hpE = hpB + (t-1)*17 + 8*w;
        float x0 = fexp2(fminf(cu[0], 15.5f));
        float x1 = fexp2(fminf(cu[1], 15.5f));
        float x2 = fexp2(fminf(cu[2], 15.5f));
        float x3 = fexp2(fminf(cu[3], 15.5f));
        hpE[2*q]   = pk2rne(x0, x1);
        hpE[2*q+1] = pk2rne(x2, x3);
      } else if (w == 2) {
        f4v cw = __builtin_amdgcn_mfma_f32_16x16x32_f16(AX[0], B0, z4, 0,0,0);
        cw     = __builtin_amdgcn_mfma_f32_16x16x32_f16(AX[1], B1, cw, 0,0,0);
        if (q == 0) ((float*)(hpB + (t-1)*17))[16] = cw[0];
      }
    }
    f4v gr = __builtin_amdgcn_mfma_f32_16x16x32_f16(Ar[0], B0, z4, 0,0,0);
    gr     = __builtin_amdgcn_mfma_f32_16x16x32_f16(Ar[1], B1, gr, 0,0,0);
    f4v gz = __builtin_amdgcn_mfma_f32_16x16x32_f16(Az[0], B0, z4, 0,0,0);
    gz     = __builtin_amdgcn_mfma_f32_16x16x32_f16(Az[1], B1, gz, 0,0,0);
    f4v gn = __builtin_amdgcn_mfma_f32_16x16x32_f16(An[0], B0, z4, 0,0,0);
    gn     = __builtin_amdgcn_mfma_f32_16x16x32_f16(An[1], B1, gn, 0,0,0);
    float xc = (float)((const _Float16*)xw)[c*130 + t];
    f4v hn;
    #pragma unroll
    for (int i = 0; i < 4; ++i) {
      float r  = fsig(fmaf(xc, wih0[i], bb0[i]) + gr[i]);
      float zf = fsig(fmaf(xc, wih1[i], bb1[i]) + gz[i]);
      float n  = ftanh(fmaf(xc, wih2[i], bi2[i]) + r*(gn[i] + bh2[i]));
      float h  = fmaf(zf, hreg[i] - n, n);
      hreg[i] = h;
      hn[i] = h;
    }
    uint2 wv; wv.x = pk2(hn[0], hn[1]); wv.y = pk2(hn[2], hn[3]);
    *(uint2*)(He[(t+1)&1] + c*72 + m0) = wv;
    WG_BARRIER_LDS();   // LDS-ordering only; hpG stores stay in flight
  }
  // ---- epilogue: Eh/hw for t=127 from He[0] (= h_127) ----
  {
    const _Float16* Hc = He[0];
    half8 B0 = __builtin_bit_cast(half8, *(const uint4*)(Hc + c*72 + 8*q));
    half8 B1 = __builtin_bit_cast(half8, *(const uint4*)(Hc + c*72 + 32 + 8*q));
    if (w < 2) {
      f4v cu = __builtin_amdgcn_mfma_f32_16x16x32_f16(AX[0], B0, z4, 0,0,0);
      cu     = __builtin_amdgcn_mfma_f32_16x16x32_f16(AX[1], B1, cu, 0,0,0);
      unsigned* hpE = hpB + 127*17 + 8*w;
      float x0 = fexp2(fminf(cu[0], 15.5f));
      float x1 = fexp2(fminf(cu[1], 15.5f));
      float x2 = fexp2(fminf(cu[2], 15.5f));
      float x3 = fexp2(fminf(cu[3], 15.5f));
      hpE[2*q]   = pk2rne(x0, x1);
      hpE[2*q+1] = pk2rne(x2, x3);
    } else if (w == 2) {
      f4v cw = __builtin_amdgcn_mfma_f32_16x16x32_f16(AX[0], B0, z4, 0,0,0);
      cw     = __builtin_amdgcn_mfma_f32_16x16x32_f16(AX[1], B1, cw, 0,0,0);
      if (q == 0) ((float*)(hpB + 127*17))[16] = cw[0];
    }
  }
  // ---- h_T (fp32) ----
  #pragma unroll
  for (int i = 0; i < 4; ++i)
    hTG[(size_t)(e0 + c)*64 + m0 + i] = hreg[i];
}

// ============ Kernel B: decoder — Eh in registers, SPILL FIXED =============
// R21: R19's reg-Eh decoder failed ONLY because launch_bounds(128,2) capped
// VGPR at 128 -> ~80 dwords spilled to scratch (WRITE_SIZE 384->21346).
// Same code with launch_bounds(128,1): VGPR budget 512, expected use ~210
// (<=256 -> still 8 waves/CU = 2/SIMD, same occupancy as the proven R16 dec).
// Removes ~64 ds_read + lgkm waits per wave-step from the beta path.
__global__ __launch_bounds__(128, 1)
void darnn_dec(const float* __restrict__ W_init, const float* __restrict__ b_init,
               const float* __restrict__ W_ih_d, const float* __restrict__ W_hh_d,
               const float* __restrict__ b_ih_d, const float* __restrict__ b_hh_d,
               const float* __restrict__ W_d, const float* __restrict__ v_d,
               const float* __restrict__ W_out, const float* __restrict__ b_out,
               const float* __restrict__ y0,
               const unsigned* __restrict__ hpG, const float* __restrict__ hTG,
               float* __restrict__ out)
{
  const int tid = threadIdx.x;
  const int wid = tid >> 6;
  const int l   = tid & 63;
  const int bA  = 4*blockIdx.x + 2*wid;
  const int bB  = bA + 1;
  const int a    = l & 31;
  const int half = l >> 5;

  __shared__ __align__(16) unsigned char smem[2304];
  unsigned char* wbp = smem + wid*1152;
  _Float16* ringA = (_Float16*)wbp;
  _Float16* ringB = (_Float16*)(wbp + 128);
  float*    dpA   = (float*)(wbp + 256);             // Edp = exp2(C2*W_d.d)
  float*    dpB   = (float*)(wbp + 384);
  float*    hTA   = (float*)(wbp + 512);
  float*    hTB   = (float*)(wbp + 768);

  // ---- Eh rows (l, 64+l) x (A,B) into registers: 68 u32 ----
  unsigned hrA0[17], hrA1[17], hrB0[17], hrB1[17];
  {
    const unsigned* pA0 = hpG + (size_t)bA*2176 + l*17;
    const unsigned* pA1 = hpG + (size_t)bA*2176 + (64+l)*17;
    const unsigned* pB0 = hpG + (size_t)bB*2176 + l*17;
    const unsigned* pB1 = hpG + (size_t)bB*2176 + (64+l)*17;
    #pragma unroll
    for (int k = 0; k < 17; ++k) {
      hrA0[k] = pA0[k]; hrA1[k] = pA1[k];
      hrB0[k] = pB0[k]; hrB1[k] = pB1[k];
    }
  }
  hTA[l] = hTG[(size_t)bA*64 + l];
  hTB[l] = hTG[(size_t)bB*64 + l];

  unsigned wr_r[32], wr_z[32], wr_n[32];
  {
    const f4v* wp = (const f4v*)W_hh_d;
    #pragma unroll
    for (int k = 0; k < 16; ++k) {
      f4v vr = wp[l*16 + k];
      f4v vz = wp[(64 + l)*16 + k];
      f4v vn = wp[(128 + l)*16 + k];
      wr_r[2*k] = pk2(vr.x, vr.y); wr_r[2*k+1] = pk2(vr.z, vr.w);
      wr_z[2*k] = pk2(vz.x, vz.y); wr_z[2*k+1] = pk2(vz.z, vz.w);
      wr_n[2*k] = pk2(vn.x, vn.y); wr_n[2*k+1] = pk2(vn.z, vn.w);
    }
  }
  float wih0 = W_ih_d[l], wih1 = W_ih_d[64+l], wih2 = W_ih_d[128+l];
  float bb0  = b_ih_d[l] + b_hh_d[l];
  float bb1  = b_ih_d[64+l] + b_hh_d[64+l];
  float bih2 = b_ih_d[128+l], bhh2 = b_hh_d[128+l];
  unsigned udr[16];
  {
    const f2* up = (const f2*)(W_d + a*64 + half*32);
    #pragma unroll
    for (int k = 0; k < 16; ++k) { f2 f = up[k]; udr[k] = pk2(f.x, f.y); }
  }
  float dprevA, dprevB;
  {
    const f4v* wi = (const f4v*)(W_init + l*64);
    const f4v* ga = (const f4v*)hTA;
    const f4v* gb = (const f4v*)hTB;
    f2 aa0={0,0}, aa1={0,0}, ba0={0,0}, ba1={0,0};
    #pragma unroll
    for (int k = 0; k < 16; ++k) {
      f4v wv = wi[k];
      f4v va = ga[k], vb = gb[k];
      aa0 = pkfma(wv.xy, va.xy, aa0);
      aa1 = pkfma(wv.zw, va.zw, aa1);
      ba0 = pkfma(wv.xy, vb.xy, ba0);
      ba1 = pkfma(wv.zw, vb.zw, ba1);
    }
    float bi = b_init[l];
    dprevA = bi + (aa0.x + aa0.y) + (aa1.x + aa1.y);
    dprevB = bi + (ba0.x + ba0.y) + (ba1.x + ba1.y);
  }
  float wout1 = W_out[l];
  float hw0A = __builtin_bit_cast(float, hrA0[16]);
  float hw1A = __builtin_bit_cast(float, hrA1[16]);
  float hw0B = __builtin_bit_cast(float, hrB0[16]);
  float hw1B = __builtin_bit_cast(float, hrB1[16]);
  float oprevA = y0[0], oprevB = y0[0];
  float bo = b_out[0];
  float c1;
  {
    float sv = v_d[a];
    sv += __shfl_xor(sv, 16); sv += __shfl_xor(sv, 8);
    sv += __shfl_xor(sv, 4);  sv += __shfl_xor(sv, 2); sv += __shfl_xor(sv, 1);
    c1 = LOG2E * sv;
  }
  ringA[l] = (_Float16)dprevA;
  ringB[l] = (_Float16)dprevB;

  #pragma unroll 1
  for (int s = 0; s < HOR; ++s) {
    float ar0A=0,ar1A=0,az0A=0,az1A=0,an0A=0,an1A=0;
    float ar0B=0,ar1B=0,az0B=0,az1B=0,an0B=0,an1B=0;
    gru_mv(ringA, wr_r, wr_z, wr_n, ar0A,ar1A,az0A,az1A,an0A,an1A);
    gru_mv(ringB, wr_r, wr_z, wr_n, ar0B,ar1B,az0B,az1B,an0B,an1B);
    float rA = fsig(fmaf(oprevA, wih0, bb0) + ar0A + ar1A);
    float zA = fsig(fmaf(oprevA, wih1, bb1) + az0A + az1A);
    float nA = ftanh(fmaf(oprevA, wih2, bih2) + rA * (an0A + an1A + bhh2));
    float dnewA = fmaf(zA, dprevA - nA, nA);
    float rB = fsig(fmaf(oprevB, wih0, bb0) + ar0B + ar1B);
    float zB = fsig(fmaf(oprevB, wih1, bb1) + az0B + az1B);
    float nB = ftanh(fmaf(oprevB, wih2, bih2) + rB * (an0B + an1B + bhh2));
    float dnewB = fmaf(zB, dprevB - nB, nB);
    dprevA = dnewA; dprevB = dnewB;
    ringA[l] = (_Float16)dnewA;
    ringB[l] = (_Float16)dnewB;
    {
      float accA = proj_dot(ringA + half*32, udr);
      float accB = proj_dot(ringB + half*32, udr);
      accA += __shfl_xor(accA, 32);
      accB += __shfl_xor(accB, 32);
      if (l < 32) {
        dpA[l] = fexp2(C2 * accA);   // Edp: one wave exp2 per elem per step
        dpB[l] = fexp2(C2 * accB);
      }
    }
    float rs0A = 0.f, rs1A = 0.f, rs0B = 0.f, rs1B = 0.f;
    #pragma unroll
    for (int j2 = 0; j2 < 8; ++j2) {
      f4v edA = *(const f4v*)&dpA[4*j2];
      f4v edB = *(const f4v*)&dpB[4*j2];
      half2_t haA0 = bch(hrA0[2*j2]), hbA0 = bch(hrA0[2*j2+1]);
      half2_t haA1 = bch(hrA1[2*j2]), hbA1 = bch(hrA1[2*j2+1]);
      half2_t haB0 = bch(hrB0[2*j2]), hbB0 = bch(hrB0[2*j2+1]);
      half2_t haB1 = bch(hrB1[2*j2]), hbB1 = bch(hrB1[2*j2+1]);
      float v0 = v_d[4*j2], v1 = v_d[4*j2+1], v2 = v_d[4*j2+2], v3 = v_d[4*j2+3];
      // sigma = 1/(1 + Edp*Eh): fma_mix + rcp, no per-element exp2
      rs0A = fmaf(v0, frcp(fmaf(edA.x, (float)haA0.x, 1.0f)), rs0A);
      rs0B = fmaf(v0, frcp(fmaf(edB.x, (float)haB0.x, 1.0f)), rs0B);
      rs0A = fmaf(v1, frcp(fmaf(edA.y, (float)haA0.y, 1.0f)), rs0A);
      rs0B = fmaf(v1, frcp(fmaf(edB.y, (float)haB0.y, 1.0f)), rs0B);
      rs0A = fmaf(v2, frcp(fmaf(edA.z, (float)hbA0.x, 1.0f)), rs0A);
      rs0B = fmaf(v2, frcp(fmaf(edB.z, (float)hbB0.x, 1.0f)), rs0B);
      rs0A = fmaf(v3, frcp(fmaf(edA.w, (float)hbA0.y, 1.0f)), rs0A);
      rs0B = fmaf(v3, frcp(fmaf(edB.w, (float)hbB0.y, 1.0f)), rs0B);
      rs1A = fmaf(v0, frcp(fmaf(edA.x, (float)haA1.x, 1.0f)), rs1A);
      rs1B = fmaf(v0, frcp(fmaf(edB.x, (float)haB1.x, 1.0f)), rs1B);
      rs1A = fmaf(v1, frcp(fmaf(edA.y, (float)haA1.y, 1.0f)), rs1A);
      rs1B = fmaf(v1, frcp(fmaf(edB.y, (float)haB1.y, 1.0f)), rs1B);
      rs1A = fmaf(v2, frcp(fmaf(edA.z, (float)hbA1.x, 1.0f)), rs1A);
      rs1B = fmaf(v2, frcp(fmaf(edB.z, (float)hbB1.x, 1.0f)), rs1B);
      rs1A = fmaf(v3, frcp(fmaf(edA.w, (float)hbA1.y, 1.0f)), rs1A);
      rs1B = fmaf(v3, frcp(fmaf(edB.w, (float)hbB1.y, 1.0f)), rs1B);
    }
    float e0A = fexp2(fmaf(-C2, rs0A, c1));
    float e1A = fexp2(fmaf(-C2, rs1A, c1));
    float e0B = fexp2(fmaf(-C2, rs0B, c1));
    float e1B = fexp2(fmaf(-C2, rs1B, c1));
    float P0A = rdl63(wavesum_dpp(e0A + e1A));
    float P1A = rdl63(wavesum_dpp(fmaf(e0A, hw0A, e1A * hw1A)));
    float P2A = rdl63(wavesum_dpp(wout1 * dnewA));
    float P0B = rdl63(wavesum_dpp(e0B + e1B));
    float P1B = rdl63(wavesum_dpp(fmaf(e0B, hw0B, e1B * hw1B)));
    float P2B = rdl63(wavesum_dpp(wout1 * dnewB));
    float oA = fmaf(P1A, frcp(P0A), P2A + bo);
    float oB = fmaf(P1B, frcp(P0B), P2B + bo);
    if (l == 0) {
      out[(size_t)bA * HOR + s] = oA;
      out[(size_t)bB * HOR + s] = oB;
    }
    oprevA = oA; oprevB = oB;
  }
}

extern "C" void kernel_launch(void* const* d_in, const int* in_sizes, int n_in,
                              void* d_out, int out_size, void* d_ws, size_t ws_size,
                              hipStream_t stream) {
  const float* x      = (const float*)d_in[0];
  const float* W_ih_e = (const float*)d_in[1];
  const float* W_hh_e = (const float*)d_in[2];
  const float* b_ih_e = (const float*)d_in[3];
  const float* b_hh_e = (const float*)d_in[4];
  // d_in[5..8] = W_e, U_e, b_e, v_e : dead (softmax over size-1 axis == 1)
  const float* W_init = (const float*)d_in[9];
  const float* b_init = (const float*)d_in[10];
  const float* W_ih_d = (const float*)d_in[11];
  const float* W_hh_d = (const float*)d_in[12];
  const float* b_ih_d = (const float*)d_in[13];
  const float* b_hh_d = (const float*)d_in[14];
  const float* W_d    = (const float*)d_in[15];
  const float* U_d    = (const float*)d_in[16];
  const float* v_d    = (const float*)d_in[17];
  const float* W_out  = (const float*)d_in[18];
  const float* b_out  = (const float*)d_in[19];
  const float* y0     = (const float*)d_in[20];
  float* outp = (float*)d_out;

  unsigned* hpG = (unsigned*)d_ws;
  float*    hTG = (float*)((char*)d_ws + (size_t)BATCH * 2176 * 4);

  darnn_enc<<<BATCH/16, 256, 0, stream>>>(x, W_ih_e, W_hh_e, b_ih_e, b_hh_e,
      U_d, W_out, hpG, hTG);
  darnn_dec<<<BATCH/4, 128, 0, stream>>>(W_init, b_init, W_ih_d, W_hh_d,
      b_ih_d, b_hh_d, W_d, v_d, W_out, b_out, y0, hpG, hTG, outp);
}

// Round 8
// 264.174 us; speedup vs baseline: 1.2250x; 1.1075x over previous
//
#include <hip/hip_runtime.h>
#include <math.h>

#define BATCH 4096
#define T 128
#define HOR 24

#define LOG2E 1.44269504088896f
#define C2    2.88539008177793f   // 2*log2(e)

typedef _Float16 half2_t __attribute__((ext_vector_type(2)));
typedef _Float16 half8   __attribute__((ext_vector_type(8)));
typedef float f2  __attribute__((ext_vector_type(2)));
typedef float f4v __attribute__((ext_vector_type(4)));

__device__ __forceinline__ float fexp2(float x){ return __builtin_amdgcn_exp2f(x); }
__device__ __forceinline__ float frcp(float x){ return __builtin_amdgcn_rcpf(x); }
__device__ __forceinline__ float fsig(float x){ return frcp(1.0f + fexp2(-LOG2E*x)); }
__device__ __forceinline__ float ftanh(float x){ return fmaf(-2.0f, frcp(1.0f + fexp2(C2*x)), 1.0f); }
__device__ __forceinline__ half2_t bch(unsigned u){ return __builtin_bit_cast(half2_t,u); }
__device__ __forceinline__ unsigned pk2(float a,float b){ return __builtin_bit_cast(unsigned, __builtin_amdgcn_cvt_pkrtz(a,b)); }
// RNE f32-pair -> packed f16 (for exp2 values: keep full fp16 accuracy, no RTZ bias)
__device__ __forceinline__ unsigned pk2rne(float a,float b){
  half2_t h; h.x = (_Float16)a; h.y = (_Float16)b;
  return __builtin_bit_cast(unsigned, h);
}
__device__ __forceinline__ float fdot2f(half2_t a, half2_t b, float c){
#if __has_builtin(__builtin_amdgcn_fdot2)
  return __builtin_amdgcn_fdot2(a,b,c,false);
#else
  return fmaf((float)a.x,(float)b.x, fmaf((float)a.y,(float)b.y,c));
#endif
}
__device__ __forceinline__ f2 pkfma(f2 a, f2 b, f2 c){ return __builtin_elementwise_fma(a,b,c); }

template <int CTRL, int RMASK>
__device__ __forceinline__ float dpp_add(float v) {
  int s = __builtin_amdgcn_update_dpp(0, __builtin_bit_cast(int, v), CTRL, RMASK, 0xf, true);
  return v + __builtin_bit_cast(float, s);
}
__device__ __forceinline__ float wavesum_dpp(float v) {
  v = dpp_add<0x111, 0xf>(v);
  v = dpp_add<0x112, 0xf>(v);
  v = dpp_add<0x114, 0xf>(v);
  v = dpp_add<0x118, 0xf>(v);
  v = dpp_add<0x142, 0xa>(v);
  v = dpp_add<0x143, 0xc>(v);
  return v;                     // total in lane 63
}
__device__ __forceinline__ float rdl63(float v){
  return __builtin_bit_cast(float, __builtin_amdgcn_readlane(__builtin_bit_cast(int, v), 63));
}

// Barrier that does NOT drain vmcnt: LDS producer/consumer ordering only.
#define WG_BARRIER_LDS() do {                                   \
    asm volatile("s_waitcnt lgkmcnt(0)" ::: "memory");          \
    __builtin_amdgcn_s_barrier();                               \
  } while (0)

__device__ __forceinline__ void gru_mv(const _Float16* hrow,
    const unsigned* wr_r, const unsigned* wr_z, const unsigned* wr_n,
    float& ar0, float& ar1, float& az0, float& az1, float& an0, float& an1)
{
  const uint4* hq = (const uint4*)hrow;
  #pragma unroll
  for (int q = 0; q < 8; ++q) {
    uint4 hv = hq[q];
    ar0 = fdot2f(bch(hv.x), bch(wr_r[4*q+0]), ar0);
    az0 = fdot2f(bch(hv.x), bch(wr_z[4*q+0]), az0);
    an0 = fdot2f(bch(hv.x), bch(wr_n[4*q+0]), an0);
    ar1 = fdot2f(bch(hv.y), bch(wr_r[4*q+1]), ar1);
    az1 = fdot2f(bch(hv.y), bch(wr_z[4*q+1]), az1);
    an1 = fdot2f(bch(hv.y), bch(wr_n[4*q+1]), an1);
    ar0 = fdot2f(bch(hv.z), bch(wr_r[4*q+2]), ar0);
    az0 = fdot2f(bch(hv.z), bch(wr_z[4*q+2]), az0);
    an0 = fdot2f(bch(hv.z), bch(wr_n[4*q+2]), an0);
    ar1 = fdot2f(bch(hv.w), bch(wr_r[4*q+3]), ar1);
    az1 = fdot2f(bch(hv.w), bch(wr_z[4*q+3]), az1);
    an1 = fdot2f(bch(hv.w), bch(wr_n[4*q+3]), an1);
  }
}

__device__ __forceinline__ float proj_dot(const _Float16* base, const unsigned* udr)
{
  float acc = 0.f;
  const uint4* hb = (const uint4*)base;
  #pragma unroll
  for (int q = 0; q < 4; ++q) {
    uint4 hv = hb[q];
    acc = fdot2f(bch(hv.x), bch(udr[4*q+0]), acc);
    acc = fdot2f(bch(hv.y), bch(udr[4*q+1]), acc);
    acc = fdot2f(bch(hv.z), bch(udr[4*q+2]), acc);
    acc = fdot2f(bch(hv.w), bch(udr[4*q+3]), acc);
  }
  return acc;
}

__device__ __forceinline__ half8 cvt8(f4v a, f4v b){
  half8 h;
  h[0]=(_Float16)a.x; h[1]=(_Float16)a.y; h[2]=(_Float16)a.z; h[3]=(_Float16)a.w;
  h[4]=(_Float16)b.x; h[5]=(_Float16)b.y; h[6]=(_Float16)b.z; h[7]=(_Float16)b.w;
  return h;
}

// 4-term grouped sigma-sum: returns acc + sum_k v_k / A_k with ONE rcp.
// A_k = 1 + Edp*Eh_k (>=1, <=~2^31.5 after clamps) -> Dc <= 2^126, no overflow;
// all terms positive, no cancellation. Exact algebra, f32 rounding ~2^-23.
__device__ __forceinline__ float grp4(float acc, f4v ed,
                                      half2_t ha, half2_t hb,
                                      float v0, float v1, float v2, float v3)
{
  float a0 = fmaf(ed.x, (float)ha.x, 1.0f);
  float a1 = fmaf(ed.y, (float)ha.y, 1.0f);
  float a2 = fmaf(ed.z, (float)hb.x, 1.0f);
  float a3 = fmaf(ed.w, (float)hb.y, 1.0f);
  float d01 = a0 * a1;
  float d23 = a2 * a3;
  float n01 = fmaf(v0, a1, v1 * a0);
  float n23 = fmaf(v2, a3, v3 * a2);
  float nc  = fmaf(n01, d23, n23 * d01);
  return fmaf(nc, frcp(d01 * d23), acc);
}

// ============ Kernel A: encoder — R15 (best measured: ~150 us) =============
// Five restructures (store-drain fix variants, chunked dump, dead-column
// 2-block, single-wave, barrier-free redistribute) all failed to beat this.
__global__ __launch_bounds__(256, 1)
void darnn_enc(const float* __restrict__ x,
               const float* __restrict__ W_ih_e, const float* __restrict__ W_hh_e,
               const float* __restrict__ b_ih_e, const float* __restrict__ b_hh_e,
               const float* __restrict__ U_d, const float* __restrict__ W_out,
               unsigned* __restrict__ hpG, float* __restrict__ hTG)
{
  const int tid = threadIdx.x;
  const int w = tid >> 6;        // wave 0..3: owns hidden units [16w,16w+16)
  const int l = tid & 63;
  const int c = l & 15;          // MFMA column = element slot
  const int q = l >> 4;          // quad
  const int e0 = blockIdx.x * 16;
  const int m0 = 16*w + 4*q;     // first of this lane's 4 hidden units

  __shared__ __align__(16) _Float16 He[2][16*72]; // ping-pong h[e][k], pad 72
  __shared__ __align__(16) unsigned xw[16*65];    // x fp16-pairs [e][65]

  // ---- stage x + zero He[0] (cooperative, all 256 threads) ----
  for (int idx = tid; idx < 16*64; idx += 256) {
    int e = idx >> 6, j = idx & 63;
    f2 g = ((const f2*)(x + (size_t)(e0+e)*T))[j];
    xw[e*65 + j] = pk2(g.x, g.y);
  }
  for (int idx = tid; idx < 576; idx += 256) ((unsigned*)He[0])[idx] = 0;

  // ---- A-frags: this wave's W_hh rows (r/z/n), 6 half8 ----
  half8 Ar[2], Az[2], An[2];
  #pragma unroll
  for (int kap = 0; kap < 2; ++kap) {
    const f4v* pr = (const f4v*)(W_hh_e + (size_t)(16*w + c)*64       + 32*kap + 8*q);
    const f4v* pz = (const f4v*)(W_hh_e + (size_t)(64 + 16*w + c)*64  + 32*kap + 8*q);
    const f4v* pn = (const f4v*)(W_hh_e + (size_t)(128 + 16*w + c)*64 + 32*kap + 8*q);
    Ar[kap] = cvt8(pr[0], pr[1]);
    Az[kap] = cvt8(pz[0], pz[1]);
    An[kap] = cvt8(pn[0], pn[1]);
  }
  // ---- Hp/hw A-frags: wave0 -> U_d rows 0..15 (xC2), wave1 -> rows 16..31,
  //      wave2 -> W_out2 (row 0 only), wave3 -> none ----
  half8 AX[2] = {{0,0,0,0,0,0,0,0},{0,0,0,0,0,0,0,0}};
  if (w < 2) {
    #pragma unroll
    for (int kap = 0; kap < 2; ++kap) {
      const f4v* p = (const f4v*)(U_d + (size_t)(16*w + c)*64 + 32*kap + 8*q);
      AX[kap] = cvt8(p[0] * C2, p[1] * C2);
    }
  } else if (w == 2 && c == 0) {
    #pragma unroll
    for (int kap = 0; kap < 2; ++kap) {
      const f4v* p = (const f4v*)(W_out + 64 + 32*kap + 8*q);
      AX[kap] = cvt8(p[0], p[1]);
    }
  }
  // ---- per-lane combine params for m0..m0+3 ----
  f4v wih0 = *(const f4v*)(W_ih_e + m0);
  f4v wih1 = *(const f4v*)(W_ih_e + 64 + m0);
  f4v wih2 = *(const f4v*)(W_ih_e + 128 + m0);
  f4v bb0  = *(const f4v*)(b_ih_e + m0)      + *(const f4v*)(b_hh_e + m0);
  f4v bb1  = *(const f4v*)(b_ih_e + 64 + m0) + *(const f4v*)(b_hh_e + 64 + m0);
  f4v bi2  = *(const f4v*)(b_ih_e + 128 + m0);
  f4v bh2  = *(const f4v*)(b_hh_e + 128 + m0);
  f4v hreg = {0,0,0,0};
  const f4v z4 = {0,0,0,0};
  unsigned* hpB = hpG + (size_t)(e0 + c) * 2176;

  __syncthreads();   // once: x staging (global loads) may drain here, fine

  // ---- 128 steps: read He[t&1], write He[(t+1)&1], 1 LDS-barrier/step ----
  #pragma unroll 1
  for (int t = 0; t < T; ++t) {
    const _Float16* Hc = He[t & 1];
    half8 B0 = __builtin_bit_cast(half8, *(const uint4*)(Hc + c*72 + 8*q));
    half8 B1 = __builtin_bit_cast(half8, *(const uint4*)(Hc + c*72 + 32 + 8*q));
    if (t > 0) {           // Eh/hw for t-1 from h_{t-1} (= the B-frags)
      if (w < 2) {
        f4v cu = __builtin_amdgcn_mfma_f32_16x16x32_f16(AX[0], B0, z4, 0,0,0);
        cu     = __builtin_amdgcn_mfma_f32_16x16x32_f16(AX[1], B1, cu, 0,0,0);
        unsigned* hpE = hpB + (t-1)*17 + 8*w;
        float x0 = fexp2(fminf(cu[0], 15.5f));
        float x1 = fexp2(fminf(cu[1], 15.5f));
        float x2 = fexp2(fminf(cu[2], 15.5f));
        float x3 = fexp2(fminf(cu[3], 15.5f));
        hpE[2*q]   = pk2rne(x0, x1);
        hpE[2*q+1] = pk2rne(x2, x3);
      } else if (w == 2) {
        f4v cw = __builtin_amdgcn_mfma_f32_16x16x32_f16(AX[0], B0, z4, 0,0,0);
        cw     = __builtin_amdgcn_mfma_f32_16x16x32_f16(AX[1], B1, cw, 0,0,0);
        if (q == 0) ((float*)(hpB + (t-1)*17))[16] = cw[0];
      }
    }
    f4v gr = __builtin_amdgcn_mfma_f32_16x16x32_f16(Ar[0], B0, z4, 0,0,0);
    gr     = __builtin_amdgcn_mfma_f32_16x16x32_f16(Ar[1], B1, gr, 0,0,0);
    f4v gz = __builtin_amdgcn_mfma_f32_16x16x32_f16(Az[0], B0, z4, 0,0,0);
    gz     = __builtin_amdgcn_mfma_f32_16x16x32_f16(Az[1], B1, gz, 0,0,0);
    f4v gn = __builtin_amdgcn_mfma_f32_16x16x32_f16(An[0], B0, z4, 0,0,0);
    gn     = __builtin_amdgcn_mfma_f32_16x16x32_f16(An[1], B1, gn, 0,0,0);
    float xc = (float)((const _Float16*)xw)[c*130 + t];
    f4v hn;
    #pragma unroll
    for (int i = 0; i < 4; ++i) {
      float r  = fsig(fmaf(xc, wih0[i], bb0[i]) + gr[i]);
      float zf = fsig(fmaf(xc, wih1[i], bb1[i]) + gz[i]);
      float n  = ftanh(fmaf(xc, wih2[i], bi2[i]) + r*(gn[i] + bh2[i]));
      float h  = fmaf(zf, hreg[i] - n, n);
      hreg[i] = h;
      hn[i] = h;
    }
    uint2 wv; wv.x = pk2(hn[0], hn[1]); wv.y = pk2(hn[2], hn[3]);
    *(uint2*)(He[(t+1)&1] + c*72 + m0) = wv;
    WG_BARRIER_LDS();   // LDS-ordering only; hpG stores stay in flight
  }
  // ---- epilogue: Eh/hw for t=127 from He[0] (= h_127) ----
  {
    const _Float16* Hc = He[0];
    half8 B0 = __builtin_bit_cast(half8, *(const uint4*)(Hc + c*72 + 8*q));
    half8 B1 = __builtin_bit_cast(half8, *(const uint4*)(Hc + c*72 + 32 + 8*q));
    if (w < 2) {
      f4v cu = __builtin_amdgcn_mfma_f32_16x16x32_f16(AX[0], B0, z4, 0,0,0);
      cu     = __builtin_amdgcn_mfma_f32_16x16x32_f16(AX[1], B1, cu, 0,0,0);
      unsigned* hpE = hpB + 127*17 + 8*w;
      float x0 = fexp2(fminf(cu[0], 15.5f));
      float x1 = fexp2(fminf(cu[1], 15.5f));
      float x2 = fexp2(fminf(cu[2], 15.5f));
      float x3 = fexp2(fminf(cu[3], 15.5f));
      hpE[2*q]   = pk2rne(x0, x1);
      hpE[2*q+1] = pk2rne(x2, x3);
    } else if (w == 2) {
      f4v cw = __builtin_amdgcn_mfma_f32_16x16x32_f16(AX[0], B0, z4, 0,0,0);
      cw     = __builtin_amdgcn_mfma_f32_16x16x32_f16(AX[1], B1, cw, 0,0,0);
      if (q == 0) ((float*)(hpB + 127*17))[16] = cw[0];
    }
  }
  // ---- h_T (fp32) ----
  #pragma unroll
  for (int i = 0; i < 4; ++i)
    hTG[(size_t)(e0 + c)*64 + m0 + i] = hreg[i];
}

// ============ Kernel B: decoder — R3 base + 4-way grouped beta rcp =========
// R22: decoder ledger says keep VGPR<=128 (4 waves/SIMD) and LDS Eh; the only
// remaining lever is instruction count. beta-loop was 128 rcp (16cy) + 256
// fma = 2560 of ~3500 issue-cy/wave-step. Grouped rational form does 4 sigma
// terms per rcp: 32 rcp + ~448 VALU = 1408 cy. Edp clamped at 2^15.5 (like
// Eh) so A<=2^31.5, Dc<=2^126: no overflow, all terms positive.
__global__ __launch_bounds__(128, 2)
void darnn_dec(const float* __restrict__ W_init, const float* __restrict__ b_init,
               const float* __restrict__ W_ih_d, const float* __restrict__ W_hh_d,
               const float* __restrict__ b_ih_d, const float* __restrict__ b_hh_d,
               const float* __restrict__ W_d, const float* __restrict__ v_d,
               const float* __restrict__ W_out, const float* __restrict__ b_out,
               const float* __restrict__ y0,
               const unsigned* __restrict__ hpG, const float* __restrict__ hTG,
               float* __restrict__ out)
{
  const int tid = threadIdx.x;
  const int wid = tid >> 6;
  const int l   = tid & 63;
  const int bA  = 4*blockIdx.x + 2*wid;
  const int bB  = bA + 1;
  const int a    = l & 31;
  const int half = l >> 5;

  __shared__ __align__(16) unsigned char smem[36928];
  unsigned char* wbp = smem + wid*18464;
  unsigned* hpA   = (unsigned*)wbp;                  // Eh fp16 pairs (+hw f32)
  unsigned* hpB   = (unsigned*)(wbp + 8704);
  _Float16* ringA = (_Float16*)(wbp + 17408);
  _Float16* ringB = (_Float16*)(wbp + 17536);
  float*    dpA   = (float*)(wbp + 17664);           // Edp = exp2(C2*W_d.d)
  float*    dpB   = (float*)(wbp + 17792);
  float*    hTA   = (float*)(wbp + 17920);
  float*    hTB   = (float*)(wbp + 18176);

  {
    const uint4* sA = (const uint4*)(hpG + (size_t)bA * 2176);
    const uint4* sB = (const uint4*)(hpG + (size_t)bB * 2176);
    #pragma unroll
    for (int it = 0; it < 8; ++it) {
      ((uint4*)hpA)[it*64 + l] = sA[it*64 + l];
      ((uint4*)hpB)[it*64 + l] = sB[it*64 + l];
    }
    const unsigned* rA = hpG + (size_t)bA*2176 + 2048;
    const unsigned* rB = hpG + (size_t)bB*2176 + 2048;
    hpA[2048 + l] = rA[l];      hpA[2112 + l] = rA[64 + l];
    hpB[2048 + l] = rB[l];      hpB[2112 + l] = rB[64 + l];
  }
  hTA[l] = hTG[(size_t)bA*64 + l];
  hTB[l] = hTG[(size_t)bB*64 + l];

  unsigned wr_r[32], wr_z[32], wr_n[32];
  {
    const f4v* wp = (const f4v*)W_hh_d;
    #pragma unroll
    for (int k = 0; k < 16; ++k) {
      f4v vr = wp[l*16 + k];
      f4v vz = wp[(64 + l)*16 + k];
      f4v vn = wp[(128 + l)*16 + k];
      wr_r[2*k] = pk2(vr.x, vr.y); wr_r[2*k+1] = pk2(vr.z, vr.w);
      wr_z[2*k] = pk2(vz.x, vz.y); wr_z[2*k+1] = pk2(vz.z, vz.w);
      wr_n[2*k] = pk2(vn.x, vn.y); wr_n[2*k+1] = pk2(vn.z, vn.w);
    }
  }
  float wih0 = W_ih_d[l], wih1 = W_ih_d[64+l], wih2 = W_ih_d[128+l];
  float bb0  = b_ih_d[l] + b_hh_d[l];
  float bb1  = b_ih_d[64+l] + b_hh_d[64+l];
  float bih2 = b_ih_d[128+l], bhh2 = b_hh_d[128+l];
  unsigned udr[16];
  {
    const f2* up = (const f2*)(W_d + a*64 + half*32);
    #pragma unroll
    for (int k = 0; k < 16; ++k) { f2 f = up[k]; udr[k] = pk2(f.x, f.y); }
  }
  float dprevA, dprevB;
  {
    const f4v* wi = (const f4v*)(W_init + l*64);
    const f4v* ga = (const f4v*)hTA;
    const f4v* gb = (const f4v*)hTB;
    f2 aa0={0,0}, aa1={0,0}, ba0={0,0}, ba1={0,0};
    #pragma unroll
    for (int k = 0; k < 16; ++k) {
      f4v wv = wi[k];
      f4v va = ga[k], vb = gb[k];
      aa0 = pkfma(wv.xy, va.xy, aa0);
      aa1 = pkfma(wv.zw, va.zw, aa1);
      ba0 = pkfma(wv.xy, vb.xy, ba0);
      ba1 = pkfma(wv.zw, vb.zw, ba1);
    }
    float bi = b_init[l];
    dprevA = bi + (aa0.x + aa0.y) + (aa1.x + aa1.y);
    dprevB = bi + (ba0.x + ba0.y) + (ba1.x + ba1.y);
  }
  float wout1 = W_out[l];
  float hw0A = __builtin_bit_cast(float, hpA[l*17 + 16]);
  float hw1A = __builtin_bit_cast(float, hpA[(64 + l)*17 + 16]);
  float hw0B = __builtin_bit_cast(float, hpB[l*17 + 16]);
  float hw1B = __builtin_bit_cast(float, hpB[(64 + l)*17 + 16]);
  float oprevA = y0[0], oprevB = y0[0];
  float bo = b_out[0];
  float c1;
  {
    float sv = v_d[a];
    sv += __shfl_xor(sv, 16); sv += __shfl_xor(sv, 8);
    sv += __shfl_xor(sv, 4);  sv += __shfl_xor(sv, 2); sv += __shfl_xor(sv, 1);
    c1 = LOG2E * sv;
  }
  ringA[l] = (_Float16)dprevA;
  ringB[l] = (_Float16)dprevB;

  const unsigned* hprA0 = hpA + l*17;
  const unsigned* hprA1 = hpA + (64 + l)*17;
  const unsigned* hprB0 = hpB + l*17;
  const unsigned* hprB1 = hpB + (64 + l)*17;

  #pragma unroll 1
  for (int s = 0; s < HOR; ++s) {
    float ar0A=0,ar1A=0,az0A=0,az1A=0,an0A=0,an1A=0;
    float ar0B=0,ar1B=0,az0B=0,az1B=0,an0B=0,an1B=0;
    gru_mv(ringA, wr_r, wr_z, wr_n, ar0A,ar1A,az0A,az1A,an0A,an1A);
    gru_mv(ringB, wr_r, wr_z, wr_n, ar0B,ar1B,az0B,az1B,an0B,an1B);
    float rA = fsig(fmaf(oprevA, wih0, bb0) + ar0A + ar1A);
    float zA = fsig(fmaf(oprevA, wih1, bb1) + az0A + az1A);
    float nA = ftanh(fmaf(oprevA, wih2, bih2) + rA * (an0A + an1A + bhh2));
    float dnewA = fmaf(zA, dprevA - nA, nA);
    float rB = fsig(fmaf(oprevB, wih0, bb0) + ar0B + ar1B);
    float zB = fsig(fmaf(oprevB, wih1, bb1) + az0B + az1B);
    float nB = ftanh(fmaf(oprevB, wih2, bih2) + rB * (an0B + an1B + bhh2));
    float dnewB = fmaf(zB, dprevB - nB, nB);
    dprevA = dnewA; dprevB = dnewB;
    ringA[l] = (_Float16)dnewA;
    ringB[l] = (_Float16)dnewB;
    {
      float accA = proj_dot(ringA + half*32, udr);
      float accB = proj_dot(ringB + half*32, udr);
      accA += __shfl_xor(accA, 32);
      accB += __shfl_xor(accB, 32);
      if (l < 32) {
        // Edp clamped like Eh so grouped products can't overflow f32
        dpA[l] = fexp2(fminf(C2 * accA, 15.5f));
        dpB[l] = fexp2(fminf(C2 * accB, 15.5f));
      }
    }
    float rs0A = 0.f, rs1A = 0.f, rs0B = 0.f, rs1B = 0.f;
    #pragma unroll
    for (int j2 = 0; j2 < 8; ++j2) {
      f4v edA = *(const f4v*)&dpA[4*j2];
      f4v edB = *(const f4v*)&dpB[4*j2];
      half2_t haA0 = bch(hprA0[2*j2]), hbA0 = bch(hprA0[2*j2+1]);
      half2_t haA1 = bch(hprA1[2*j2]), hbA1 = bch(hprA1[2*j2+1]);
      half2_t haB0 = bch(hprB0[2*j2]), hbB0 = bch(hprB0[2*j2+1]);
      half2_t haB1 = bch(hprB1[2*j2]), hbB1 = bch(hprB1[2*j2+1]);
      float v0 = v_d[4*j2], v1 = v_d[4*j2+1], v2 = v_d[4*j2+2], v3 = v_d[4*j2+3];
      rs0A = grp4(rs0A, edA, haA0, hbA0, v0, v1, v2, v3);
      rs0B = grp4(rs0B, edB, haB0, hbB0, v0, v1, v2, v3);
      rs1A = grp4(rs1A, edA, haA1, hbA1, v0, v1, v2, v3);
      rs1B = grp4(rs1B, edB, haB1, hbB1, v0, v1, v2, v3);
    }
    float e0A = fexp2(fmaf(-C2, rs0A, c1));
    float e1A = fexp2(fmaf(-C2, rs1A, c1));
    float e0B = fexp2(fmaf(-C2, rs0B, c1));
    float e1B = fexp2(fmaf(-C2, rs1B, c1));
    float P0A = rdl63(wavesum_dpp(e0A + e1A));
    float P1A = rdl63(wavesum_dpp(fmaf(e0A, hw0A, e1A * hw1A)));
    float P2A = rdl63(wavesum_dpp(wout1 * dnewA));
    float P0B = rdl63(wavesum_dpp(e0B + e1B));
    float P1B = rdl63(wavesum_dpp(fmaf(e0B, hw0B, e1B * hw1B)));
    float P2B = rdl63(wavesum_dpp(wout1 * dnewB));
    float oA = fmaf(P1A, frcp(P0A), P2A + bo);
    float oB = fmaf(P1B, frcp(P0B), P2B + bo);
    if (l == 0) {
      out[(size_t)bA * HOR + s] = oA;
      out[(size_t)bB * HOR + s] = oB;
    }
    oprevA = oA; oprevB = oB;
  }
}

extern "C" void kernel_launch(void* const* d_in, const int* in_sizes, int n_in,
                              void* d_out, int out_size, void* d_ws, size_t ws_size,
                              hipStream_t stream) {
  const float* x      = (const float*)d_in[0];
  const float* W_ih_e = (const float*)d_in[1];
  const float* W_hh_e = (const float*)d_in[2];
  const float* b_ih_e = (const float*)d_in[3];
  const float* b_hh_e = (const float*)d_in[4];
  // d_in[5..8] = W_e, U_e, b_e, v_e : dead (softmax over size-1 axis == 1)
  const float* W_init = (const float*)d_in[9];
  const float* b_init = (const float*)d_in[10];
  const float* W_ih_d = (const float*)d_in[11];
  const float* W_hh_d = (const float*)d_in[12];
  const float* b_ih_d = (const float*)d_in[13];
  const float* b_hh_d = (const float*)d_in[14];
  const float* W_d    = (const float*)d_in[15];
  const float* U_d    = (const float*)d_in[16];
  const float* v_d    = (const float*)d_in[17];
  const float* W_out  = (const float*)d_in[18];
  const float* b_out  = (const float*)d_in[19];
  const float* y0     = (const float*)d_in[20];
  float* outp = (float*)d_out;

  unsigned* hpG = (unsigned*)d_ws;
  float*    hTG = (float*)((char*)d_ws + (size_t)BATCH * 2176 * 4);

  darnn_enc<<<BATCH/16, 256, 0, stream>>>(x, W_ih_e, W_hh_e, b_ih_e, b_hh_e,
      U_d, W_out, hpG, hTG);
  darnn_dec<<<BATCH/4, 128, 0, stream>>>(W_init, b_init, W_ih_d, W_hh_d,
      b_ih_d, b_hh_d, W_d, v_d, W_out, b_out, y0, hpG, hTG, outp);
}